// Round 1
// baseline (399.968 us; speedup 1.0000x reference)
//
#include <hip/hip_runtime.h>

// PointConv: B=4, N=16384, K=32, F=64
// out[b,n,f] = sum_k ( lrelu(rel_pos(b,n,k) @ W1 + b1) @ W2 + b2 )[f] * x[b, idx[b,n,k], f]
//
// Round 1: fp32 VALU baseline.
//  - one wave per point (lane = feature f), 4 waves/block
//  - W2 column f held in 64 VGPRs per lane (coalesced preload)
//  - h staged per-wave in LDS, broadcast-read as float4 in the matvec
//  - compute-bound: ~17.2 GFLOP dominated by the 64x64 matvec per (point,k)

#define NPTS   16384
#define KNB    32
#define F      64
#define BATCH  4
#define LOG2N  14

__global__ __launch_bounds__(256) void pointconv_kernel(
    const float* __restrict__ x,
    const float* __restrict__ pos,
    const int*   __restrict__ idx,
    const float* __restrict__ W1,
    const float* __restrict__ b1,
    const float* __restrict__ W2,
    const float* __restrict__ b2,
    float*       __restrict__ out)
{
    __shared__ __align__(16) float hbuf[4][KNB][F];   // 32 KB/block

    const int lane = threadIdx.x & 63;
    const int wv   = threadIdx.x >> 6;
    const int p    = blockIdx.x * 4 + wv;       // global point id in [0, B*N)
    const int b    = p >> LOG2N;                // batch
    const int base = b << LOG2N;                // b*N

    // per-lane weights (lane = output feature f)
    const float w10 = W1[0 * F + lane];
    const float w11 = W1[1 * F + lane];
    const float w12 = W1[2 * F + lane];
    const float b1v = b1[lane];
    const float b2v = b2[lane];

    // W2 column f in registers: w2r[g] = W2[g][f]
    float w2r[F];
#pragma unroll
    for (int g = 0; g < F; ++g) w2r[g] = W2[g * F + lane];

    // own position (wave-uniform loads, L2-resident)
    const float px = pos[p * 3 + 0];
    const float py = pos[p * 3 + 1];
    const float pz = pos[p * 3 + 2];

    // ---- phase 1: h[k][f] = lrelu(rel @ W1 + b1) for all k ----
#pragma unroll 4
    for (int k = 0; k < KNB; ++k) {
        const int j   = idx[p * KNB + k];
        const int row = base + j;
        const float rx = px - pos[row * 3 + 0];
        const float ry = py - pos[row * 3 + 1];
        const float rz = pz - pos[row * 3 + 2];
        float a = fmaf(rx, w10, fmaf(ry, w11, fmaf(rz, w12, b1v)));
        hbuf[wv][k][lane] = fmaxf(a, 0.1f * a);   // leaky_relu(a, 0.1)
    }
    __syncthreads();

    // ---- phase 2: w[f] = h @ W2 + b2 ; acc += w[f] * x[j][f] ----
    float acc = 0.f;
#pragma unroll 2
    for (int k = 0; k < KNB; ++k) {
        const int j  = idx[p * KNB + k];
        const float xv = x[(base + j) * F + lane];
        float wsum = b2v;
        const float4* h4 = (const float4*)&hbuf[wv][k][0];
#pragma unroll
        for (int g4 = 0; g4 < F / 4; ++g4) {
            const float4 h = h4[g4];                 // broadcast ds_read_b128
            wsum = fmaf(h.x, w2r[4 * g4 + 0], wsum);
            wsum = fmaf(h.y, w2r[4 * g4 + 1], wsum);
            wsum = fmaf(h.z, w2r[4 * g4 + 2], wsum);
            wsum = fmaf(h.w, w2r[4 * g4 + 3], wsum);
        }
        acc = fmaf(wsum, xv, acc);
    }

    out[p * F + lane] = acc;
}

extern "C" void kernel_launch(void* const* d_in, const int* in_sizes, int n_in,
                              void* d_out, int out_size, void* d_ws, size_t ws_size,
                              hipStream_t stream) {
    const float* x   = (const float*)d_in[0];
    const float* pos = (const float*)d_in[1];
    const int*   idx = (const int*)  d_in[2];
    const float* W1  = (const float*)d_in[3];
    const float* b1  = (const float*)d_in[4];
    const float* W2  = (const float*)d_in[5];
    const float* b2  = (const float*)d_in[6];
    float* out = (float*)d_out;

    dim3 grid((BATCH * NPTS) / 4);   // one wave per point, 4 waves per block
    dim3 block(256);
    pointconv_kernel<<<grid, block, 0, stream>>>(x, pos, idx, W1, b1, W2, b2, out);
}

// Round 2
// 259.599 us; speedup vs baseline: 1.5407x; 1.5407x over previous
//
#include <hip/hip_runtime.h>

// PointConv: B=4, N=16384, K=32, F=64
// out[p,f] = sum_k ( lrelu(rel(p,k) @ W1 + b1) @ W2 + b2 )[f] * x[idx[p,k], f]
//
// Round 2: bf16 MFMA for the 64x64 matvec (batched as [32k x 64g] @ [64g x 64f]
// per point, v_mfma_f32_32x32x16_bf16, 8 MFMA/point).
//  - one wave per point-iteration, WPTS=8 points/wave to amortize W2 fragments
//  - A-fragments (h) computed directly in A-layout: lane owns neighbor m=lane&31,
//    g = 16t + (lane>>5)*8 + j; W1 columns broadcast from LDS as float4
//  - W2 held in B-layout bf16 fragments in 32 VGPRs (loaded once per wave)
//  - epilogue: C-layout row k -> __shfl idx from lane k, fp32 gather-FMA of x,
//    halves merged with __shfl_xor(32)
// Only H and W2 are bf16 (RNE); everything else fp32.

#define NPTS   16384
#define KNB    32
#define F      64
#define BATCH  4
#define LOG2N  14
#define WPTS   8

typedef short  bf16x8 __attribute__((ext_vector_type(8)));
typedef float  f32x16 __attribute__((ext_vector_type(16)));

static __device__ __forceinline__ short f32_bf16(float f) {
    // round-to-nearest-even bf16, bit pattern in a short
    unsigned int u = __builtin_bit_cast(unsigned int, f);
    u += 0x7FFFu + ((u >> 16) & 1u);
    return (short)(u >> 16);
}

__global__ __launch_bounds__(256) void pointconv_mfma(
    const float* __restrict__ x,
    const float* __restrict__ pos,
    const int*   __restrict__ idx,
    const float* __restrict__ W1,
    const float* __restrict__ b1,
    const float* __restrict__ W2,
    const float* __restrict__ b2,
    float*       __restrict__ out)
{
    // W1 columns packed for 1-instr broadcast reads: (W1[0][g], W1[1][g], W1[2][g], b1[g])
    __shared__ float4 w1lds[F];
    const int tid = threadIdx.x;
    if (tid < F) {
        w1lds[tid] = make_float4(W1[0 * F + tid], W1[1 * F + tid],
                                 W1[2 * F + tid], b1[tid]);
    }
    __syncthreads();

    const int lane = tid & 63;
    const int wv   = tid >> 6;
    const int m    = lane & 31;   // MFMA row ownership (neighbor slot) / f within tile
    const int half = lane >> 5;   // k-half of the A/B fragments

    // ---- W2 in B-fragment layout, once per wave ----
    // b_frag[t][c][j] = bf16( W2[g][f] ), g = 16t + half*8 + j, f = 32c + m
    bf16x8 bfrag[4][2];
#pragma unroll
    for (int t = 0; t < 4; ++t)
#pragma unroll
        for (int c = 0; c < 2; ++c)
#pragma unroll
            for (int j = 0; j < 8; ++j) {
                const int g = 16 * t + half * 8 + j;
                bfrag[t][c][j] = f32_bf16(W2[g * F + 32 * c + m]);
            }
    const float b20 = b2[m];
    const float b21 = b2[32 + m];

    const int wave_id = blockIdx.x * 4 + wv;

    for (int i = 0; i < WPTS; ++i) {
        const int p    = wave_id * WPTS + i;      // point id in [0, B*N)
        const int base = (p >> LOG2N) << LOG2N;   // b*N

        // ---- step A: rel_pos for this lane's neighbor m ----
        const float px = pos[p * 3 + 0];
        const float py = pos[p * 3 + 1];
        const float pz = pos[p * 3 + 2];
        const int   jm   = idx[p * KNB + m];
        const int   nrow = base + jm;
        const float rx = px - pos[nrow * 3 + 0];
        const float ry = py - pos[nrow * 3 + 1];
        const float rz = pz - pos[nrow * 3 + 2];

        f32x16 acc0, acc1;
#pragma unroll
        for (int r = 0; r < 16; ++r) { acc0[r] = 0.f; acc1[r] = 0.f; }

        // ---- step B+D: h in A-layout, MFMA over g in 4 steps of 16 ----
#pragma unroll
        for (int t = 0; t < 4; ++t) {
            bf16x8 af;
#pragma unroll
            for (int j = 0; j < 8; ++j) {
                const int g = 16 * t + half * 8 + j;
                const float4 w1v = w1lds[g];                 // LDS broadcast (2 addrs/wave)
                float a = fmaf(rx, w1v.x, fmaf(ry, w1v.y, fmaf(rz, w1v.z, w1v.w)));
                a = fmaxf(a, 0.1f * a);                      // leaky_relu(a, 0.1)
                af[j] = f32_bf16(a);
            }
            acc0 = __builtin_amdgcn_mfma_f32_32x32x16_bf16(af, bfrag[t][0], acc0, 0, 0, 0);
            acc1 = __builtin_amdgcn_mfma_f32_32x32x16_bf16(af, bfrag[t][1], acc1, 0, 0, 0);
        }

        // ---- step E: weighted sum over k with gathered x (fp32) ----
        // C layout: col f = (lane&31)+32c, row k = (reg&3) + 8*(reg>>2) + 4*half
        float s0 = 0.f, s1 = 0.f;
#pragma unroll
        for (int reg = 0; reg < 16; ++reg) {
            const int row = (reg & 3) + ((reg >> 2) << 3) + (half << 2);
            const int jk  = __shfl(jm, row);                 // idx[p, row] from lane `row`
            const float* xr = x + (size_t)(base + jk) * F;
            const float xv0 = xr[m];
            const float xv1 = xr[32 + m];
            s0 = fmaf(acc0[reg] + b20, xv0, s0);
            s1 = fmaf(acc1[reg] + b21, xv1, s1);
        }
        // halves hold disjoint k-rows for the same f: merge
        s0 += __shfl_xor(s0, 32);
        s1 += __shfl_xor(s1, 32);

        out[p * F + half * 32 + m] = half ? s1 : s0;
    }
}

extern "C" void kernel_launch(void* const* d_in, const int* in_sizes, int n_in,
                              void* d_out, int out_size, void* d_ws, size_t ws_size,
                              hipStream_t stream) {
    const float* x   = (const float*)d_in[0];
    const float* pos = (const float*)d_in[1];
    const int*   idx = (const int*)  d_in[2];
    const float* W1  = (const float*)d_in[3];
    const float* b1  = (const float*)d_in[4];
    const float* W2  = (const float*)d_in[5];
    const float* b2  = (const float*)d_in[6];
    float* out = (float*)d_out;

    // 65536 points / (4 waves * WPTS points) per block
    dim3 grid((BATCH * NPTS) / (4 * WPTS));
    dim3 block(256);
    pointconv_mfma<<<grid, block, 0, stream>>>(x, pos, idx, W1, b1, W2, b2, out);
}

// Round 3
// 163.563 us; speedup vs baseline: 2.4454x; 1.5872x over previous
//
#include <hip/hip_runtime.h>

// PointConv: B=4, N=16384, K=32, F=64
// out[p,f] = sum_k ( lrelu(rel(p,k) @ W1 + b1) @ W2 + b2 )[f] * x[idx[p,k], f]
//
// Round 3: same MFMA core as round 2 (v_mfma_f32_32x32x16_bf16, verified
// layouts), restructured against latency:
//  - WPTS=4 points/wave; idx + pos gathers for all 4 points hoisted up front
//  - x-gather loads issued BEFORE h/MFMA of the same point (dep only on idx)
//  - W2 staged through LDS transposed [f][g] (pad 72) -> 8 ds_read_b128/wave
//  - W1+b1 in LDS as packed f16x4 (half the broadcast return-bus traffic)
//  - RNE bf16 pair-pack via v_perm_b32

#define NPTS   16384
#define KNB    32
#define F      64
#define BATCH  4
#define LOG2N  14
#define WPTS   4

typedef short    bf16x8 __attribute__((ext_vector_type(8)));
typedef float    f32x16 __attribute__((ext_vector_type(16)));
typedef _Float16 half4  __attribute__((ext_vector_type(4)));

static __device__ __forceinline__ unsigned rne_hi(float f) {
    unsigned u = __builtin_bit_cast(unsigned, f);
    return u + 0x7FFFu + ((u >> 16) & 1u);   // RNE-rounded, bf16 in high 16 bits
}
static __device__ __forceinline__ int pack2_bf16(float lo, float hi) {
    // (hi_bf16 << 16) | lo_bf16 in one v_perm_b32
    return (int)__builtin_amdgcn_perm(rne_hi(hi), rne_hi(lo), 0x07060302u);
}

__global__ __launch_bounds__(256, 2) void pointconv_mfma(
    const float* __restrict__ x,
    const float* __restrict__ pos,
    const int*   __restrict__ idx,
    const float* __restrict__ W1,
    const float* __restrict__ b1,
    const float* __restrict__ W2,
    const float* __restrict__ b2,
    float*       __restrict__ out)
{
    __shared__ __align__(16) half4 w1lds[F];       // (W1x, W1y, W1z, b1) per g, f16
    __shared__ __align__(16) short w2lds[F][72];   // bf16 W2 transposed [f][g], pad->16B align

    const int tid = threadIdx.x;
    if (tid < F) {
        w1lds[tid] = (half4){ (_Float16)W1[0 * F + tid], (_Float16)W1[1 * F + tid],
                              (_Float16)W1[2 * F + tid], (_Float16)b1[tid] };
    }
#pragma unroll
    for (int r = 0; r < 16; ++r) {                 // 256 threads x 16 = 4096 elems, coalesced
        const int e = r * 256 + tid;
        const int g = e >> 6, f = e & 63;
        w2lds[f][g] = (short)(rne_hi(W2[e]) >> 16);
    }
    __syncthreads();

    const int lane = tid & 63;
    const int wv   = tid >> 6;
    const int m    = lane & 31;    // MFMA row (neighbor slot) / f within 32-tile
    const int half = lane >> 5;    // k-half of A/B fragments

    // ---- B fragments from LDS: bfrag[t][c][j] = bf16(W2[16t+8*half+j][32c+m]) ----
    bf16x8 bfrag[4][2];
#pragma unroll
    for (int t = 0; t < 4; ++t)
#pragma unroll
        for (int c = 0; c < 2; ++c)
            bfrag[t][c] = *(const bf16x8*)&w2lds[32 * c + m][16 * t + 8 * half];

    const float b20 = b2[m];
    const float b21 = b2[32 + m];

    const int p0   = (blockIdx.x * 4 + wv) * WPTS;
    const int base = (p0 >> LOG2N) << LOG2N;       // same batch for all WPTS points

    // ---- stage 1: idx for all points (coalesced, independent) ----
    int jm[WPTS];
#pragma unroll
    for (int i = 0; i < WPTS; ++i) jm[i] = idx[(p0 + i) * KNB + m];

    // ---- stage 2: own pos + neighbor pos gathers for all points ----
    float rx[WPTS], ry[WPTS], rz[WPTS];
#pragma unroll
    for (int i = 0; i < WPTS; ++i) {
        const int p = p0 + i;
        const float px = pos[p * 3 + 0];
        const float py = pos[p * 3 + 1];
        const float pz = pos[p * 3 + 2];
        const int nr = base + jm[i];
        rx[i] = px - pos[nr * 3 + 0];
        ry[i] = py - pos[nr * 3 + 1];
        rz[i] = pz - pos[nr * 3 + 2];
    }

    // ---- stage 3: per point ----
#pragma unroll
    for (int i = 0; i < WPTS; ++i) {
        const int p = p0 + i;

        // 3a: x-gather issued first (depends only on idx) — lands during h/MFMA
        float xa[16], xb[16];
#pragma unroll
        for (int reg = 0; reg < 16; ++reg) {
            const int row = (reg & 3) + ((reg >> 2) << 3) + (half << 2);
            const int jk  = __shfl(jm[i], row);
            const float* xr = x + (size_t)(base + jk) * F;
            xa[reg] = xr[m];
            xb[reg] = xr[32 + m];
        }

        // 3b: h in A-layout + MFMA over g (4 steps of 16)
        f32x16 acc0, acc1;
#pragma unroll
        for (int r = 0; r < 16; ++r) { acc0[r] = 0.f; acc1[r] = 0.f; }

#pragma unroll
        for (int t = 0; t < 4; ++t) {
            int hpk[4];
#pragma unroll
            for (int jj = 0; jj < 4; ++jj) {
                float hv[2];
#pragma unroll
                for (int s = 0; s < 2; ++s) {
                    const int g = 16 * t + 8 * half + 2 * jj + s;
                    const half4 w = w1lds[g];                    // b64 broadcast
                    float a = (float)w[3];
                    a = fmaf(rx[i], (float)w[0], a);             // v_fma_mix
                    a = fmaf(ry[i], (float)w[1], a);
                    a = fmaf(rz[i], (float)w[2], a);
                    hv[s] = fmaxf(a, 0.1f * a);                  // leaky_relu
                }
                hpk[jj] = pack2_bf16(hv[0], hv[1]);
            }
            const bf16x8 af = __builtin_bit_cast(bf16x8, *(int4*)hpk);
            acc0 = __builtin_amdgcn_mfma_f32_32x32x16_bf16(af, bfrag[t][0], acc0, 0, 0, 0);
            acc1 = __builtin_amdgcn_mfma_f32_32x32x16_bf16(af, bfrag[t][1], acc1, 0, 0, 0);
        }

        // 3c: epilogue — w = acc + b2, out += w * x  (two partial chains for ILP)
        float s0a = 0.f, s0b = 0.f, s1a = 0.f, s1b = 0.f;
#pragma unroll
        for (int reg = 0; reg < 16; reg += 2) {
            s0a = fmaf(acc0[reg]     + b20, xa[reg],     s0a);
            s0b = fmaf(acc0[reg + 1] + b20, xa[reg + 1], s0b);
            s1a = fmaf(acc1[reg]     + b21, xb[reg],     s1a);
            s1b = fmaf(acc1[reg + 1] + b21, xb[reg + 1], s1b);
        }
        float s0 = s0a + s0b, s1 = s1a + s1b;
        s0 += __shfl_xor(s0, 32);                  // merge k-halves
        s1 += __shfl_xor(s1, 32);
        out[p * F + half * 32 + m] = half ? s1 : s0;
    }
}

extern "C" void kernel_launch(void* const* d_in, const int* in_sizes, int n_in,
                              void* d_out, int out_size, void* d_ws, size_t ws_size,
                              hipStream_t stream) {
    const float* x   = (const float*)d_in[0];
    const float* pos = (const float*)d_in[1];
    const int*   idx = (const int*)  d_in[2];
    const float* W1  = (const float*)d_in[3];
    const float* b1  = (const float*)d_in[4];
    const float* W2  = (const float*)d_in[5];
    const float* b2  = (const float*)d_in[6];
    float* out = (float*)d_out;

    // 65536 points / (4 waves * WPTS points) per block
    dim3 grid((BATCH * NPTS) / (4 * WPTS));
    dim3 block(256);
    pointconv_mfma<<<grid, block, 0, stream>>>(x, pos, idx, W1, b1, W2, b2, out);
}